// Round 3
// baseline (174.303 us; speedup 1.0000x reference)
//
#include <hip/hip_runtime.h>

#define NTHREADS 256

#if defined(__has_builtin)
#if __has_builtin(__builtin_amdgcn_exp2f)
#define EXP2F __builtin_amdgcn_exp2f
#else
#define EXP2F exp2f
#endif
#else
#define EXP2F exp2f
#endif

__device__ __forceinline__ float rfl(float x) {
    return __uint_as_float(__builtin_amdgcn_readfirstlane(__float_as_uint(x)));
}

// 4 sigmoids with 2 shared reciprocals: 4 exp2 + 2 rcp (instead of 4+4 trans).
// sigmoid(a) = 1/(1+exp2(-log2e*a)); rel err of pairing ~2e-5, far below threshold.
__device__ __forceinline__ void sigm4(const float a[4], float s[4]) {
    const float c = -1.442695040888963f;
    float d0 = 1.0f + EXP2F(a[0] * c);
    float d1 = 1.0f + EXP2F(a[1] * c);
    float d2 = 1.0f + EXP2F(a[2] * c);
    float d3 = 1.0f + EXP2F(a[3] * c);
    float r01 = __builtin_amdgcn_rcpf(d0 * d1);
    float r23 = __builtin_amdgcn_rcpf(d2 * d3);
    s[0] = r01 * d1;
    s[1] = r01 * d0;
    s[2] = r23 * d3;
    s[3] = r23 * d2;
}

__global__ __launch_bounds__(NTHREADS, 8)
void mlp6_fused_kernel(const float* __restrict__ xl,
                       const float* __restrict__ yl,
                       const float* __restrict__ xr,
                       const float* __restrict__ W1, const float* __restrict__ b1,
                       const float* __restrict__ W2, const float* __restrict__ b2,
                       const float* __restrict__ W3_2, const float* __restrict__ b3_2,
                       const float* __restrict__ W3_1, const float* __restrict__ b3_1,
                       const float* __restrict__ W4, const float* __restrict__ b4,
                       float* __restrict__ out, int B)
{
    const int tid = threadIdx.x;
    const int nq = B >> 2;                       // groups of 4 samples
    int gq = blockIdx.x * NTHREADS + tid;
    if (gq >= nq) gq = nq - 1;                   // dup-writes are identical

    // --- vector-load 4 consecutive samples (20 floats = 5 float4) per array ---
    float bl[20], by[20], br_[20];
    {
        const float4* a4 = (const float4*)xl;
        const float4* y4 = (const float4*)yl;
        const float4* c4 = (const float4*)xr;
        int p = gq * 5;
        #pragma unroll
        for (int q = 0; q < 5; q++) {
            ((float4*)bl)[q]  = a4[p + q];
            ((float4*)by)[q]  = y4[p + q];
            ((float4*)br_)[q] = c4[p + q];
        }
    }

    // --- fold fc3(+fc4) into per-branch 4-vector fw + output bias fbv ---
    // Uniform values; pin to SGPRs via readfirstlane.
    // W3_2 flat [4][2][4] rows j=0..3 <-> branches {0,1,4,5}; W4 flat [2][1][4];
    // W3_1 flat [2][1][4]; b3_2 flat [4][2]; b3_1 flat [2][1]; b4 flat [2][1].
    float fw[6][4];
    #pragma unroll
    for (int h = 0; h < 4; h++) {
        fw[0][h] = rfl(fmaf(W4[1], W3_2[4 + h],  W4[0] * W3_2[h]));
        fw[1][h] = rfl(fmaf(W4[5], W3_2[12 + h], W4[4] * W3_2[8 + h]));
        fw[2][h] = rfl(W3_1[h]);
        fw[3][h] = rfl(W3_1[4 + h]);
        fw[4][h] = rfl(fmaf(W4[3], W3_2[20 + h], W4[2] * W3_2[16 + h]));
        fw[5][h] = rfl(fmaf(W4[7], W3_2[28 + h], W4[6] * W3_2[24 + h]));
    }
    float fbv[4];
    fbv[0] = rfl(b3_1[0]);
    fbv[1] = rfl(b3_1[1]);
    fbv[2] = rfl(W4[0]*b3_2[0] + W4[1]*b3_2[1] + W4[2]*b3_2[4] + W4[3]*b3_2[5] + b4[0]);
    fbv[3] = rfl(W4[4]*b3_2[2] + W4[5]*b3_2[3] + W4[6]*b3_2[6] + W4[7]*b3_2[7] + b4[1]);

    float o[4][4];   // [slot][s]
    #pragma unroll
    for (int j = 0; j < 4; j++) {
        #pragma unroll
        for (int s = 0; s < 4; s++) o[j][s] = fbv[j];
    }

    // --- one branch MLP over 4 samples; weights via uniform (scalar) loads ---
    auto branch = [&](int k, const float* xb, int slot) {
        float h1[4][4];   // [h][s]
        #pragma unroll
        for (int h = 0; h < 4; h++) {
            float a[4];
            float bb = b1[k*4 + h];
            #pragma unroll
            for (int s = 0; s < 4; s++) a[s] = bb;
            #pragma unroll
            for (int i = 0; i < 5; i++) {
                float wv = W1[k*20 + h*5 + i];
                #pragma unroll
                for (int s = 0; s < 4; s++) a[s] = fmaf(xb[s*5 + i], wv, a[s]);
            }
            sigm4(a, h1[h]);
        }
        #pragma unroll
        for (int g = 0; g < 4; g++) {
            float a[4];
            float bb = b2[k*4 + g];
            #pragma unroll
            for (int s = 0; s < 4; s++) a[s] = bb;
            #pragma unroll
            for (int h = 0; h < 4; h++) {
                float wv = W2[k*16 + g*4 + h];
                #pragma unroll
                for (int s = 0; s < 4; s++) a[s] = fmaf(h1[h][s], wv, a[s]);
            }
            float t[4];
            sigm4(a, t);
            float fg = fw[k][g];
            #pragma unroll
            for (int s = 0; s < 4; s++) o[slot][s] = fmaf(t[s], fg, o[slot][s]);
        }
    };

    // X = stack([xl, yl, xr, yl, xl, yl]); slots: br2->0, br3->1, {br0,br4}->2, {br1,br5}->3
    branch(0, bl, 2);
    branch(4, bl, 2);
    branch(1, by, 3);
    branch(3, by, 1);
    branch(5, by, 3);
    branch(2, br_, 0);

    float4* out4 = (float4*)out;
    #pragma unroll
    for (int s = 0; s < 4; s++) {
        float4 r;
        r.x = o[0][s]; r.y = o[1][s]; r.z = o[2][s]; r.w = o[3][s];
        out4[gq*4 + s] = r;
    }
}

extern "C" void kernel_launch(void* const* d_in, const int* in_sizes, int n_in,
                              void* d_out, int out_size, void* d_ws, size_t ws_size,
                              hipStream_t stream) {
    const float* xl   = (const float*)d_in[0];
    const float* yl   = (const float*)d_in[1];
    const float* xr   = (const float*)d_in[2];
    // d_in[3] = yr — unused by the reference forward
    const float* W1   = (const float*)d_in[4];
    const float* b1   = (const float*)d_in[5];
    const float* W2   = (const float*)d_in[6];
    const float* b2   = (const float*)d_in[7];
    const float* W3_2 = (const float*)d_in[8];
    const float* b3_2 = (const float*)d_in[9];
    const float* W3_1 = (const float*)d_in[10];
    const float* b3_1 = (const float*)d_in[11];
    const float* W4   = (const float*)d_in[12];
    const float* b4   = (const float*)d_in[13];
    float* out = (float*)d_out;

    int B = in_sizes[0] / 5;               // 2,000,000 (divisible by 4)
    int nq = B >> 2;
    int blocks = (nq + NTHREADS - 1) / NTHREADS;
    mlp6_fused_kernel<<<blocks, NTHREADS, 0, stream>>>(
        xl, yl, xr, W1, b1, W2, b2, W3_2, b3_2, W3_1, b3_1, W4, b4, out, B);
}

// Round 4
// 47.096 us; speedup vs baseline: 3.7010x; 3.7010x over previous
//
#include <hip/hip_runtime.h>

#define NTHREADS 256

#if defined(__has_builtin)
#if __has_builtin(__builtin_amdgcn_exp2f)
#define EXP2F __builtin_amdgcn_exp2f
#else
#define EXP2F exp2f
#endif
#else
#define EXP2F exp2f
#endif

__device__ __forceinline__ float rfl(float x) {
    return __uint_as_float(__builtin_amdgcn_readfirstlane(__float_as_uint(x)));
}

// 4 sigmoids, 2 shared reciprocals (4 exp2 + 2 rcp). In-place.
// sigmoid(a) = 1/(1+exp2(-log2e*a)); pairing rel-err ~2e-5 << 1.4e-2 threshold.
__device__ __forceinline__ void sigm4(float a[4]) {
    const float c = -1.442695040888963f;
    float d0 = 1.0f + EXP2F(a[0] * c);
    float d1 = 1.0f + EXP2F(a[1] * c);
    float d2 = 1.0f + EXP2F(a[2] * c);
    float d3 = 1.0f + EXP2F(a[3] * c);
    float r01 = __builtin_amdgcn_rcpf(d0 * d1);
    float r23 = __builtin_amdgcn_rcpf(d2 * d3);
    a[0] = r01 * d1;
    a[1] = r01 * d0;
    a[2] = r23 * d3;
    a[3] = r23 * d2;
}

__global__ __launch_bounds__(NTHREADS, 8)
void mlp6_fused_kernel(const float* __restrict__ xl,
                       const float* __restrict__ yl,
                       const float* __restrict__ xr,
                       const float* __restrict__ W1, const float* __restrict__ b1,
                       const float* __restrict__ W2, const float* __restrict__ b2,
                       const float* __restrict__ W3_2, const float* __restrict__ b3_2,
                       const float* __restrict__ W3_1, const float* __restrict__ b3_1,
                       const float* __restrict__ W4, const float* __restrict__ b4,
                       float* __restrict__ out, int B)
{
    int i = blockIdx.x * NTHREADS + threadIdx.x;
    if (i >= B) i = B - 1;                 // dup-writes are identical
    const int p = i * 5;

    // SPT=1: only 10 input floats live at peak (xr reuses xl's registers).
    float xa[5], ya[5];
    #pragma unroll
    for (int q = 0; q < 5; q++) xa[q] = xl[p + q];
    #pragma unroll
    for (int q = 0; q < 5; q++) ya[q] = yl[p + q];

    // --- fold fc3(+fc4) into per-branch 4-vector fw + output bias fbv ---
    // Uniform; pinned to SGPRs via readfirstlane. Constant-indexed after inlining.
    // W3_2 flat [4][2][4] rows j=0..3 <-> branches {0,1,4,5}; W4 flat [2][1][4];
    // W3_1 flat [2][1][4]; b3_2 flat [4][2]; b3_1 flat [2][1]; b4 flat [2][1].
    float fw[6][4];
    #pragma unroll
    for (int h = 0; h < 4; h++) {
        fw[0][h] = rfl(fmaf(W4[1], W3_2[4 + h],  W4[0] * W3_2[h]));
        fw[1][h] = rfl(fmaf(W4[5], W3_2[12 + h], W4[4] * W3_2[8 + h]));
        fw[2][h] = rfl(W3_1[h]);
        fw[3][h] = rfl(W3_1[4 + h]);
        fw[4][h] = rfl(fmaf(W4[3], W3_2[20 + h], W4[2] * W3_2[16 + h]));
        fw[5][h] = rfl(fmaf(W4[7], W3_2[28 + h], W4[6] * W3_2[24 + h]));
    }
    float o0 = rfl(b3_1[0]);
    float o1 = rfl(b3_1[1]);
    float o2 = rfl(W4[0]*b3_2[0] + W4[1]*b3_2[1] + W4[2]*b3_2[4] + W4[3]*b3_2[5] + b4[0]);
    float o3 = rfl(W4[4]*b3_2[2] + W4[5]*b3_2[3] + W4[6]*b3_2[6] + W4[7]*b3_2[7] + b4[1]);

    // --- one branch MLP for one sample; weights via uniform (scalar) loads ---
    auto branch = [&](int k, const float* xb) -> float {
        float a[4];
        #pragma unroll
        for (int h = 0; h < 4; h++) {
            float s = b1[k*4 + h];
            #pragma unroll
            for (int q = 0; q < 5; q++) s = fmaf(xb[q], W1[k*20 + h*5 + q], s);
            a[h] = s;
        }
        sigm4(a);
        float c[4];
        #pragma unroll
        for (int g = 0; g < 4; g++) {
            float s = b2[k*4 + g];
            #pragma unroll
            for (int h = 0; h < 4; h++) s = fmaf(a[h], W2[k*16 + g*4 + h], s);
            c[g] = s;
        }
        sigm4(c);
        float r = c[0] * fw[k][0];
        #pragma unroll
        for (int g = 1; g < 4; g++) r = fmaf(c[g], fw[k][g], r);
        return r;
    };

    // X = stack([xl, yl, xr, yl, xl, yl]); slots: br2->o0, br3->o1, {br0,br4}->o2, {br1,br5}->o3
    o2 += branch(0, xa);
    o2 += branch(4, xa);
    // xl dead: prefetch xr into its registers; latency hides under yl branches
    #pragma unroll
    for (int q = 0; q < 5; q++) xa[q] = xr[p + q];
    o3 += branch(1, ya);
    o1 += branch(3, ya);
    o3 += branch(5, ya);
    o0 += branch(2, xa);

    float4 r;
    r.x = o0; r.y = o1; r.z = o2; r.w = o3;
    ((float4*)out)[i] = r;                 // lane-consecutive 16B: fully coalesced
}

extern "C" void kernel_launch(void* const* d_in, const int* in_sizes, int n_in,
                              void* d_out, int out_size, void* d_ws, size_t ws_size,
                              hipStream_t stream) {
    const float* xl   = (const float*)d_in[0];
    const float* yl   = (const float*)d_in[1];
    const float* xr   = (const float*)d_in[2];
    // d_in[3] = yr — unused by the reference forward
    const float* W1   = (const float*)d_in[4];
    const float* b1   = (const float*)d_in[5];
    const float* W2   = (const float*)d_in[6];
    const float* b2   = (const float*)d_in[7];
    const float* W3_2 = (const float*)d_in[8];
    const float* b3_2 = (const float*)d_in[9];
    const float* W3_1 = (const float*)d_in[10];
    const float* b3_1 = (const float*)d_in[11];
    const float* W4   = (const float*)d_in[12];
    const float* b4   = (const float*)d_in[13];
    float* out = (float*)d_out;

    int B = in_sizes[0] / 5;               // 2,000,000
    int blocks = (B + NTHREADS - 1) / NTHREADS;
    mlp6_fused_kernel<<<blocks, NTHREADS, 0, stream>>>(
        xl, yl, xr, W1, b1, W2, b2, W3_2, b3_2, W3_1, b3_1, W4, b4, out, B);
}

// Round 6
// 39.470 us; speedup vs baseline: 4.4161x; 1.1932x over previous
//
#include <hip/hip_runtime.h>

#define NTHREADS 256

typedef float f32x2 __attribute__((ext_vector_type(2)));

#if defined(__has_builtin)
#if __has_builtin(__builtin_amdgcn_exp2f)
#define EXP2F __builtin_amdgcn_exp2f
#else
#define EXP2F exp2f
#endif
#else
#define EXP2F exp2f
#endif

__device__ __forceinline__ float rfl(float x) {
    return __uint_as_float(__builtin_amdgcn_readfirstlane(__float_as_uint(x)));
}

__device__ __forceinline__ f32x2 bc2(float w) {
    f32x2 r; r.x = w; r.y = w; return r;
}
__device__ __forceinline__ f32x2 pfma(f32x2 a, f32x2 b, f32x2 c) {
    return __builtin_elementwise_fma(a, b, c);
}

// 4 sigmoids x 2 samples (f32x2 lanes = the 2 samples), reciprocal shared
// 4-ways per element: 8 exp2 + 2 rcp + ~17 packed VALU.
// sigmoid(a) = 1/(1+exp2(-log2e*a)). With |a| <~ 20 all intermediates < 2^88:
// no overflow, no NaN. Sharing rel-err ~2e-6 << 1.4e-2 threshold.
__device__ __forceinline__ void sig4(f32x2 v[4]) {
    const f32x2 C   = bc2(-1.442695040888963f);
    const f32x2 ONE = bc2(1.0f);
    f32x2 d[4];
    #pragma unroll
    for (int h = 0; h < 4; h++) {
        f32x2 m = v[h] * C;
        f32x2 e; e.x = EXP2F(m.x); e.y = EXP2F(m.y);
        d[h] = e + ONE;
    }
    f32x2 p01 = d[0] * d[1];
    f32x2 p23 = d[2] * d[3];
    f32x2 P   = p01 * p23;
    f32x2 r;
    r.x = __builtin_amdgcn_rcpf(P.x);
    r.y = __builtin_amdgcn_rcpf(P.y);
    f32x2 r01 = r * p23;   // = 1/(d0*d1)
    f32x2 r23 = r * p01;   // = 1/(d2*d3)
    v[0] = r01 * d[1];
    v[1] = r01 * d[0];
    v[2] = r23 * d[3];
    v[3] = r23 * d[2];
}

__global__ __launch_bounds__(NTHREADS, 4)
void mlp6_fused_kernel(const float* __restrict__ xl,
                       const float* __restrict__ yl,
                       const float* __restrict__ xr,
                       const float* __restrict__ W1, const float* __restrict__ b1,
                       const float* __restrict__ W2, const float* __restrict__ b2,
                       const float* __restrict__ W3_2, const float* __restrict__ b3_2,
                       const float* __restrict__ W3_1, const float* __restrict__ b3_1,
                       const float* __restrict__ W4, const float* __restrict__ b4,
                       float* __restrict__ out, int B)
{
    const int nq = B >> 1;                     // sample pairs
    int gq = blockIdx.x * NTHREADS + threadIdx.x;
    if (gq >= nq) gq = nq - 1;                 // dup-writes are identical

    // ---- load 2 samples x 5 feats per array as 5x dwordx2 (8B-aligned) ----
    f32x2 LA[5], LB[5], LC[5];
    {
        const f32x2* x2 = (const f32x2*)xl + (long long)gq * 5;
        const f32x2* y2 = (const f32x2*)yl + (long long)gq * 5;
        const f32x2* c2 = (const f32x2*)xr + (long long)gq * 5;
        #pragma unroll
        for (int q = 0; q < 5; q++) LA[q] = x2[q];
        #pragma unroll
        for (int q = 0; q < 5; q++) LB[q] = y2[q];
        #pragma unroll
        for (int q = 0; q < 5; q++) LC[q] = c2[q];
    }
    // repack to per-feature sample-pairs: xp[q] = {x[s0][q], x[s1][q]}
    // s0 floats f0..f4 ; s1 floats f5..f9 across LA[0..4]
    f32x2 xp[5], yp[5];
    xp[0].x = LA[0].x; xp[0].y = LA[2].y;
    xp[1].x = LA[0].y; xp[1].y = LA[3].x;
    xp[2].x = LA[1].x; xp[2].y = LA[3].y;
    xp[3].x = LA[1].y; xp[3].y = LA[4].x;
    xp[4].x = LA[2].x; xp[4].y = LA[4].y;
    yp[0].x = LB[0].x; yp[0].y = LB[2].y;
    yp[1].x = LB[0].y; yp[1].y = LB[3].x;
    yp[2].x = LB[1].x; yp[2].y = LB[3].y;
    yp[3].x = LB[1].y; yp[3].y = LB[4].x;
    yp[4].x = LB[2].x; yp[4].y = LB[4].y;

    // ---- fold fc3(+fc4): per-branch 4-vec fw + output biases (uniform) ----
    // W3_2 flat [4][2][4] rows j=0..3 <-> branches {0,1,4,5}; W4 flat [2][1][4];
    // W3_1 flat [2][1][4]; b3_2 flat [4][2]; b3_1 flat [2][1]; b4 flat [2][1].
    float fw[6][4];
    #pragma unroll
    for (int h = 0; h < 4; h++) {
        fw[0][h] = rfl(fmaf(W4[1], W3_2[4 + h],  W4[0] * W3_2[h]));
        fw[1][h] = rfl(fmaf(W4[5], W3_2[12 + h], W4[4] * W3_2[8 + h]));
        fw[2][h] = rfl(W3_1[h]);
        fw[3][h] = rfl(W3_1[4 + h]);
        fw[4][h] = rfl(fmaf(W4[3], W3_2[20 + h], W4[2] * W3_2[16 + h]));
        fw[5][h] = rfl(fmaf(W4[7], W3_2[28 + h], W4[6] * W3_2[24 + h]));
    }
    float fb0 = rfl(b3_1[0]);
    float fb1 = rfl(b3_1[1]);
    float fb2 = rfl(W4[0]*b3_2[0] + W4[1]*b3_2[1] + W4[2]*b3_2[4] + W4[3]*b3_2[5] + b4[0]);
    float fb3 = rfl(W4[4]*b3_2[2] + W4[5]*b3_2[3] + W4[6]*b3_2[6] + W4[7]*b3_2[7] + b4[1]);

    f32x2 o0 = bc2(fb0), o1 = bc2(fb1), o2 = bc2(fb2), o3 = bc2(fb3);

    // ---- one branch over a sample pair, packed v2f32 ----
    auto branch = [&](int k, const f32x2 (&in)[5], f32x2& oslot) {
        f32x2 h[4];
        #pragma unroll
        for (int hh = 0; hh < 4; hh++) {
            f32x2 acc = bc2(b1[k*4 + hh]);
            #pragma unroll
            for (int q = 0; q < 5; q++)
                acc = pfma(in[q], bc2(W1[k*20 + hh*5 + q]), acc);
            h[hh] = acc;
        }
        sig4(h);
        f32x2 c[4];
        #pragma unroll
        for (int g = 0; g < 4; g++) {
            f32x2 acc = bc2(b2[k*4 + g]);
            #pragma unroll
            for (int q = 0; q < 4; q++)
                acc = pfma(h[q], bc2(W2[k*16 + g*4 + q]), acc);
            c[g] = acc;
        }
        sig4(c);
        #pragma unroll
        for (int g = 0; g < 4; g++)
            oslot = pfma(c[g], bc2(fw[k][g]), oslot);
    };

    // X = stack([xl, yl, xr, yl, xl, yl]); slots: br2->o0, br3->o1, {br0,br4}->o2, {br1,br5}->o3
    branch(0, xp, o2);
    branch(4, xp, o2);
    // xl consumed -> repack xr into xp (LC loaded up top, long since landed)
    xp[0].x = LC[0].x; xp[0].y = LC[2].y;
    xp[1].x = LC[0].y; xp[1].y = LC[3].x;
    xp[2].x = LC[1].x; xp[2].y = LC[3].y;
    xp[3].x = LC[1].y; xp[3].y = LC[4].x;
    xp[4].x = LC[2].x; xp[4].y = LC[4].y;
    branch(1, yp, o3);
    branch(3, yp, o1);
    branch(5, yp, o3);
    branch(2, xp, o0);

    float4 r0, r1;
    r0.x = o0.x; r0.y = o1.x; r0.z = o2.x; r0.w = o3.x;
    r1.x = o0.y; r1.y = o1.y; r1.z = o2.y; r1.w = o3.y;
    float4* out4 = (float4*)out;
    out4[(long long)gq * 2]     = r0;   // lane-consecutive 32B: fully coalesced
    out4[(long long)gq * 2 + 1] = r1;
}

extern "C" void kernel_launch(void* const* d_in, const int* in_sizes, int n_in,
                              void* d_out, int out_size, void* d_ws, size_t ws_size,
                              hipStream_t stream) {
    const float* xl   = (const float*)d_in[0];
    const float* yl   = (const float*)d_in[1];
    const float* xr   = (const float*)d_in[2];
    // d_in[3] = yr — unused by the reference forward
    const float* W1   = (const float*)d_in[4];
    const float* b1   = (const float*)d_in[5];
    const float* W2   = (const float*)d_in[6];
    const float* b2   = (const float*)d_in[7];
    const float* W3_2 = (const float*)d_in[8];
    const float* b3_2 = (const float*)d_in[9];
    const float* W3_1 = (const float*)d_in[10];
    const float* b3_1 = (const float*)d_in[11];
    const float* W4   = (const float*)d_in[12];
    const float* b4   = (const float*)d_in[13];
    float* out = (float*)d_out;

    int B = in_sizes[0] / 5;               // 2,000,000 (even)
    int nq = B >> 1;
    int blocks = (nq + NTHREADS - 1) / NTHREADS;
    mlp6_fused_kernel<<<blocks, NTHREADS, 0, stream>>>(
        xl, yl, xr, W1, b1, W2, b2, W3_2, b3_2, W3_1, b3_1, W4, b4, out, B);
}